// Round 2
// baseline (175.177 us; speedup 1.0000x reference)
//
#include <hip/hip_runtime.h>

typedef __attribute__((ext_vector_type(4))) float f32x4;
typedef __attribute__((ext_vector_type(4))) int i32x4;
typedef __attribute__((ext_vector_type(8))) short short8;
typedef unsigned int u32;
typedef unsigned long long u64;
typedef unsigned short u16;

#define NB 512
#define TT 256
#define CC 384
#define HH 64

__device__ __forceinline__ u16 fbf(float f) {
    u32 u = __builtin_bit_cast(u32, f);
    u32 r = u + 0x7fffu + ((u >> 16) & 1u);
    return (u16)(r >> 16);
}

// pack two f32 -> two bf16 (RNE) in one instruction
__device__ __forceinline__ u32 cvtpk(float lo, float hi) {
    u32 r;
    asm("v_cvt_pk_bf16_f32 %0, %1, %2" : "=v"(r) : "v"(lo), "v"(hi));
    return r;
}

__device__ __forceinline__ f32x4 mfma16x16x32(short8 a, short8 b, f32x4 c) {
    return __builtin_amdgcn_mfma_f32_16x16x32_bf16(a, b, c, 0, 0, 0);
}

// WbT layout: fragment fi = ((mat*12 + kt)*4 + nt); element (fi*64 + lane)*8 + j
//   = W[mat][c = 32*kt + 8*(lane>>4) + j][h = 16*nt + (lane&15)]
// mat 0 = Wq * 384^-0.5 (scale folded), 1 = Wk, 2 = Wv.
__global__ __launch_bounds__(256) void prep_w(const float* __restrict__ Wk,
                                              const float* __restrict__ Wq,
                                              const float* __restrict__ Wv,
                                              u16* __restrict__ WbT) {
    int t = blockIdx.x * 256 + threadIdx.x;
    if (t >= 144 * 64) return;
    int lane = t & 63;
    int fi = t >> 6;
    int mat = fi / 48;
    int kt = (fi >> 2) % 12;
    int nt = fi & 3;
    const float* W = (mat == 0) ? Wq : (mat == 1 ? Wk : Wv);
    float scale = (mat == 0) ? 0.05103103630798288f : 1.0f;
    int c0 = 32 * kt + 8 * (lane >> 4);
    int h = 16 * nt + (lane & 15);
#pragma unroll
    for (int j = 0; j < 8; ++j)
        WbT[(size_t)t * 8 + j] = fbf(W[(c0 + j) * HH + h] * scale);
}

// One block per batch, 8 waves, LDS 64KB -> 2 blocks/CU.
// Wave w owns two 16-row q-tiles: rows [16w,16w+16) and [240-16w,256-16w)
// (pairs low+high causal cost -> every wave does ~equal attention work).
// K row-major [256][64] bf16 (XOR-swizzled), Vt [64][256] bf16 (swizzled).
// Q-fragment transpose reuses the wave's own K rows before K is written.
// P reshape (S^T D-layout -> PV A-fragment) done fully in-register via shfl.
__global__ __launch_bounds__(512, 4) void attn_head(const float* __restrict__ x,
                                                    const u16* __restrict__ WbT,
                                                    float* __restrict__ out) {
    __shared__ __align__(16) u16 Klds[TT * HH];
    __shared__ __align__(16) u16 Vtlds[HH * TT];

    const int tid = (int)threadIdx.x;
    const int lane = tid & 63;
    const int w = tid >> 6;
    const int c = lane & 15;
    const int g = lane >> 4;
    const int b = (int)blockIdx.x;
    const int grow0 = 16 * w;
    const int grow1 = 240 - 16 * w;

    char* kbase = (char*)Klds;
    char* vbase = (char*)Vtlds;
    const float* xb = x + (size_t)b * TT * CC;

    short8 Qf[2][2];

    // ---------------- projection (per tile, sequential to cap registers) ----------------
#pragma unroll
    for (int tm = 0; tm < 2; ++tm) {
        const int gr = (tm == 0) ? grow0 : grow1;
        f32x4 acc[3][4];
#pragma unroll
        for (int m = 0; m < 3; ++m)
#pragma unroll
            for (int nt = 0; nt < 4; ++nt)
                acc[m][nt] = (f32x4){0.f, 0.f, 0.f, 0.f};

        for (int kt = 0; kt < 12; ++kt) {
            const float* p = xb + (size_t)(gr + c) * CC + 32 * kt + 8 * g;
            f32x4 f0 = *(const f32x4*)p;
            f32x4 f1 = *(const f32x4*)(p + 4);
            i32x4 aw = {(int)cvtpk(f0[0], f0[1]), (int)cvtpk(f0[2], f0[3]),
                        (int)cvtpk(f1[0], f1[1]), (int)cvtpk(f1[2], f1[3])};
            short8 afr = __builtin_bit_cast(short8, aw);
#pragma unroll
            for (int mat = 0; mat < 3; ++mat)
#pragma unroll
                for (int nt = 0; nt < 4; ++nt) {
                    short8 bfr = *(const short8*)(WbT + (size_t)(((mat * 12 + kt) * 4 + nt) * 64 + lane) * 8);
                    acc[mat][nt] = mfma16x16x32(afr, bfr, acc[mat][nt]);
                }
        }

        // Q: D-layout -> own K rows (scratch) -> B-fragments
#pragma unroll
        for (int nt = 0; nt < 4; ++nt)
#pragma unroll
            for (int r = 0; r < 4; ++r) {
                int q = gr + 4 * g + r;
                int hh = 16 * nt + c;
                *(u16*)(kbase + q * 128 + ((hh * 2) ^ ((q & 7) << 4))) = fbf(acc[0][nt][r]);
            }
#pragma unroll
        for (int kt = 0; kt < 2; ++kt) {
            int q = gr + c;
            Qf[tm][kt] = *(const short8*)(kbase + q * 128 + ((64 * kt + 16 * g) ^ ((q & 7) << 4)));
        }

        // K (overwrites Q scratch rows; same-wave DS ordering) and Vt
#pragma unroll
        for (int nt = 0; nt < 4; ++nt) {
            int hh = 16 * nt + c;
#pragma unroll
            for (int r = 0; r < 4; ++r) {
                int s = gr + 4 * g + r;
                *(u16*)(kbase + s * 128 + ((hh * 2) ^ ((s & 7) << 4))) = fbf(acc[1][nt][r]);
            }
            int sb4 = gr + 4 * g;
            u64 pkv = (u64)cvtpk(acc[2][nt][0], acc[2][nt][1]) |
                      ((u64)cvtpk(acc[2][nt][2], acc[2][nt][3]) << 32);
            *(u64*)(vbase + hh * 512 + ((sb4 * 2) ^ ((hh & 7) << 4))) = pkv;
        }
    }

    __syncthreads();

    // ---------------- attention: online softmax over 64-wide s-chunks ----------------
    float m_run0 = -1e30f, m_run1 = -1e30f, l_run0 = 0.f, l_run1 = 0.f;
    f32x4 o0[4], o1[4];
#pragma unroll
    for (int ht = 0; ht < 4; ++ht) {
        o0[ht] = (f32x4){0.f, 0.f, 0.f, 0.f};
        o1[ht] = (f32x4){0.f, 0.f, 0.f, 0.f};
    }

    const int lastc0 = (grow0 + 15) >> 6;
    const int lastc1 = (grow1 + 15) >> 6;  // >= lastc0 always
    const int srcLo = c + ((lane & 16) << 1);  // c + 32*(g&1)
    const int srcHi = srcLo + 16;
    const bool hiHalf = (lane >= 32);

    for (int ci = 0; ci <= lastc1; ++ci) {
        const int s0 = 64 * ci;
        const bool act0 = (ci <= lastc0);
        const int stmax0 = act0 ? min(3, (grow0 + 15 - s0) >> 4) : -1;
        const int stmax1 = min(3, (grow1 + 15 - s0) >> 4);  // tm1 active for all ci
        const int stmaxU = max(stmax0, stmax1);

        // S^T = K(16s x 32h) x Q^T(32h x 16q); lane: s-row = 4g+r, q-col = c
        f32x4 SS0[4], SS1[4];
#pragma unroll
        for (int st = 0; st < 4; ++st) {
            SS0[st] = (f32x4){0.f, 0.f, 0.f, 0.f};
            SS1[st] = (f32x4){0.f, 0.f, 0.f, 0.f};
        }
#pragma unroll
        for (int kt = 0; kt < 2; ++kt) {
#pragma unroll
            for (int st = 0; st < 4; ++st) {
                if (st <= stmaxU) {
                    int s = s0 + 16 * st + c;
                    short8 kf = *(const short8*)(kbase + s * 128 + ((64 * kt + 16 * g) ^ ((s & 7) << 4)));
                    if (st <= stmax0) SS0[st] = mfma16x16x32(kf, Qf[0][kt], SS0[st]);
                    if (st <= stmax1) SS1[st] = mfma16x16x32(kf, Qf[1][kt], SS1[st]);
                }
            }
        }

        // causal mask + chunk max
        float mx0 = -1e30f, mx1 = -1e30f;
        const int qg0 = grow0 + c, qg1 = grow1 + c;
#pragma unroll
        for (int st = 0; st < 4; ++st) {
#pragma unroll
            for (int r = 0; r < 4; ++r) {
                int sg = s0 + 16 * st + 4 * g + r;
                if (st <= stmax0) {
                    float v = (sg > qg0) ? -1e30f : SS0[st][r];
                    SS0[st][r] = v;
                    mx0 = fmaxf(mx0, v);
                }
                if (st <= stmax1) {
                    float v = (sg > qg1) ? -1e30f : SS1[st][r];
                    SS1[st][r] = v;
                    mx1 = fmaxf(mx1, v);
                }
            }
        }
        if (act0) {
            mx0 = fmaxf(mx0, __shfl_xor(mx0, 16));
            mx0 = fmaxf(mx0, __shfl_xor(mx0, 32));
        }
        mx1 = fmaxf(mx1, __shfl_xor(mx1, 16));
        mx1 = fmaxf(mx1, __shfl_xor(mx1, 32));

        float fs0 = 1.f, fs1;
        if (act0) {
            float mn0 = fmaxf(m_run0, mx0);
            fs0 = __expf(m_run0 - mn0);
            m_run0 = mn0;
        }
        {
            float mn1 = fmaxf(m_run1, mx1);
            fs1 = __expf(m_run1 - mn1);
            m_run1 = mn1;
        }

        float ls0 = 0.f, ls1 = 0.f;
#pragma unroll
        for (int st = 0; st < 4; ++st) {
#pragma unroll
            for (int r = 0; r < 4; ++r) {
                if (st <= stmax0) {
                    float p = __expf(SS0[st][r] - m_run0);
                    SS0[st][r] = p;
                    ls0 += p;
                }
                if (st <= stmax1) {
                    float p = __expf(SS1[st][r] - m_run1);
                    SS1[st][r] = p;
                    ls1 += p;
                }
            }
        }
        if (act0) {
            ls0 += __shfl_xor(ls0, 16);
            ls0 += __shfl_xor(ls0, 32);
            l_run0 = l_run0 * fs0 + ls0;
        }
        ls1 += __shfl_xor(ls1, 16);
        ls1 += __shfl_xor(ls1, 32);
        l_run1 = l_run1 * fs1 + ls1;

        // rescale O (row q = 4g+r holds fs in lane c'=4g+r)
#pragma unroll
        for (int r = 0; r < 4; ++r) {
            float fr0 = __shfl(fs0, 4 * g + r);
            float fr1 = __shfl(fs1, 4 * g + r);
#pragma unroll
            for (int ht = 0; ht < 4; ++ht) {
                if (act0) o0[ht][r] *= fr0;
                o1[ht][r] *= fr1;
            }
        }

        // pack P to bf16 pairs: pk[st][word]; word0 = s-offsets {4g,4g+1}, word1 = {4g+2,4g+3}
        u32 pk0[4][2], pk1[4][2];
#pragma unroll
        for (int st = 0; st < 4; ++st) {
            pk0[st][0] = cvtpk(SS0[st][0], SS0[st][1]);
            pk0[st][1] = cvtpk(SS0[st][2], SS0[st][3]);
            pk1[st][0] = cvtpk(SS1[st][0], SS1[st][1]);
            pk1[st][1] = cvtpk(SS1[st][2], SS1[st][3]);
        }

        // PV: O += P(16q x 32s) x V(32s x 16h); P A-fragment built via shfl:
        // word i of lane (g',c) = pk[2ks+(g'>>1)][i&1] from lane c+32*(g'&1)+16*(i>>1)
        const int ksmax0 = stmax0 >> 1;  // -1 stays -1
        const int ksmax1 = stmax1 >> 1;
#pragma unroll
        for (int ks = 0; ks < 2; ++ks) {
            const bool u0 = (ks <= ksmax0);
            const bool u1 = (ks <= ksmax1);
            if (!(u0 || u1)) continue;
            short8 Pf0, Pf1;
            if (u0) {
                u32 a0 = (u32)__shfl((int)pk0[2 * ks][0], srcLo);
                u32 b0 = (u32)__shfl((int)pk0[2 * ks + 1][0], srcLo);
                u32 a1 = (u32)__shfl((int)pk0[2 * ks][1], srcLo);
                u32 b1 = (u32)__shfl((int)pk0[2 * ks + 1][1], srcLo);
                u32 a2 = (u32)__shfl((int)pk0[2 * ks][0], srcHi);
                u32 b2 = (u32)__shfl((int)pk0[2 * ks + 1][0], srcHi);
                u32 a3 = (u32)__shfl((int)pk0[2 * ks][1], srcHi);
                u32 b3 = (u32)__shfl((int)pk0[2 * ks + 1][1], srcHi);
                i32x4 t = {(int)(hiHalf ? b0 : a0), (int)(hiHalf ? b1 : a1),
                           (int)(hiHalf ? b2 : a2), (int)(hiHalf ? b3 : a3)};
                Pf0 = __builtin_bit_cast(short8, t);
            }
            if (u1) {
                u32 a0 = (u32)__shfl((int)pk1[2 * ks][0], srcLo);
                u32 b0 = (u32)__shfl((int)pk1[2 * ks + 1][0], srcLo);
                u32 a1 = (u32)__shfl((int)pk1[2 * ks][1], srcLo);
                u32 b1 = (u32)__shfl((int)pk1[2 * ks + 1][1], srcLo);
                u32 a2 = (u32)__shfl((int)pk1[2 * ks][0], srcHi);
                u32 b2 = (u32)__shfl((int)pk1[2 * ks + 1][0], srcHi);
                u32 a3 = (u32)__shfl((int)pk1[2 * ks][1], srcHi);
                u32 b3 = (u32)__shfl((int)pk1[2 * ks + 1][1], srcHi);
                i32x4 t = {(int)(hiHalf ? b0 : a0), (int)(hiHalf ? b1 : a1),
                           (int)(hiHalf ? b2 : a2), (int)(hiHalf ? b3 : a3)};
                Pf1 = __builtin_bit_cast(short8, t);
            }
#pragma unroll
            for (int ht = 0; ht < 4; ++ht) {
                int hh = 16 * ht + c;
                short8 vf = *(const short8*)(vbase + hh * 512 + ((2 * s0 + 64 * ks + 16 * g) ^ ((hh & 7) << 4)));
                if (u0) o0[ht] = mfma16x16x32(Pf0, vf, o0[ht]);
                if (u1) o1[ht] = mfma16x16x32(Pf1, vf, o1[ht]);
            }
        }
    }

    // ---------------- epilogue ----------------
    float ri0 = 1.f / l_run0, ri1 = 1.f / l_run1;
    float* ob0 = out + ((size_t)b * TT + grow0) * HH;
    float* ob1 = out + ((size_t)b * TT + grow1) * HH;
#pragma unroll
    for (int r = 0; r < 4; ++r) {
        float rr0 = __shfl(ri0, 4 * g + r);
        float rr1 = __shfl(ri1, 4 * g + r);
#pragma unroll
        for (int ht = 0; ht < 4; ++ht) {
            ob0[(4 * g + r) * HH + 16 * ht + c] = o0[ht][r] * rr0;
            ob1[(4 * g + r) * HH + 16 * ht + c] = o1[ht][r] * rr1;
        }
    }
}

extern "C" void kernel_launch(void* const* d_in, const int* in_sizes, int n_in,
                              void* d_out, int out_size, void* d_ws, size_t ws_size,
                              hipStream_t stream) {
    (void)in_sizes; (void)n_in; (void)out_size; (void)ws_size;
    const float* x = (const float*)d_in[0];
    const float* Wk = (const float*)d_in[1];
    const float* Wq = (const float*)d_in[2];
    const float* Wv = (const float*)d_in[3];
    u16* WbT = (u16*)d_ws;
    float* out = (float*)d_out;

    prep_w<<<36, 256, 0, stream>>>(Wk, Wq, Wv, WbT);
    attn_head<<<NB, 512, 0, stream>>>(x, WbT, out);
}

// Round 4
// 129.235 us; speedup vs baseline: 1.3555x; 1.3555x over previous
//
#include <hip/hip_runtime.h>

typedef __attribute__((ext_vector_type(4))) float f32x4;
typedef __attribute__((ext_vector_type(4))) int i32x4;
typedef __attribute__((ext_vector_type(8))) short short8;
typedef unsigned int u32;
typedef unsigned long long u64;
typedef unsigned short u16;

#define NB 512
#define TT 256
#define CC 384
#define HH 64

__device__ __forceinline__ u16 fbf(float f) {
    u32 u = __builtin_bit_cast(u32, f);
    u32 r = u + 0x7fffu + ((u >> 16) & 1u);
    return (u16)(r >> 16);
}

// pack two f32 -> two bf16 (RNE) in one instruction
__device__ __forceinline__ u32 cvtpk(float lo, float hi) {
    u32 r;
    asm("v_cvt_pk_bf16_f32 %0, %1, %2" : "=v"(r) : "v"(lo), "v"(hi));
    return r;
}

__device__ __forceinline__ f32x4 mfma16x16x32(short8 a, short8 b, f32x4 c) {
    return __builtin_amdgcn_mfma_f32_16x16x32_bf16(a, b, c, 0, 0, 0);
}

// WbT layout: fragment fi = ((mat*12 + kt)*4 + nt); element (fi*64 + lane)*8 + j
//   = W[mat][c = 32*kt + 8*(lane>>4) + j][h = 16*nt + (lane&15)]
// mat 0 = Wq * 384^-0.5 (scale folded), 1 = Wk, 2 = Wv.
__global__ __launch_bounds__(256) void prep_w(const float* __restrict__ Wk,
                                              const float* __restrict__ Wq,
                                              const float* __restrict__ Wv,
                                              u16* __restrict__ WbT) {
    int t = blockIdx.x * 256 + threadIdx.x;
    if (t >= 144 * 64) return;
    int lane = t & 63;
    int fi = t >> 6;
    int mat = fi / 48;
    int kt = (fi >> 2) % 12;
    int nt = fi & 3;
    const float* W = (mat == 0) ? Wq : (mat == 1 ? Wk : Wv);
    float scale = (mat == 0) ? 0.05103103630798288f : 1.0f;
    int c0 = 32 * kt + 8 * (lane >> 4);
    int h = 16 * nt + (lane & 15);
#pragma unroll
    for (int j = 0; j < 8; ++j)
        WbT[(size_t)t * 8 + j] = fbf(W[(c0 + j) * HH + h] * scale);
}

// One block per batch, 8 waves, LDS 80KB -> 2 blocks/CU.
// Wave w owns two 16-row q-tiles: rows [16w,16w+16) and [240-16w,256-16w),
// processed SEQUENTIALLY (one tile's state live -> no spills); the pairing
// keeps causal attention work ~equal (~5 chunk-iters) across waves.
// K row-major [256][64] bf16 (XOR-swizzled), Vt [64][256] bf16 (swizzled),
// per-wave 16x64 P scratch (2KB) for the S^T D-layout -> PV A-frag reshape.
// NOTE: PV reads P s-blocks st <= (stmax|1); the write loop MUST cover that
// range (zeros beyond stmax) -- reading unwritten LDS was round-3's NaN.
__global__ __launch_bounds__(512, 4) void attn_head(const float* __restrict__ x,
                                                    const u16* __restrict__ WbT,
                                                    float* __restrict__ out) {
    __shared__ __align__(16) u16 Klds[TT * HH];      // 32 KB
    __shared__ __align__(16) u16 Vtlds[HH * TT];     // 32 KB
    __shared__ __align__(16) u16 Pscr[8 * 16 * 64];  // 16 KB

    const int tid = (int)threadIdx.x;
    const int lane = tid & 63;
    const int w = tid >> 6;
    const int c = lane & 15;
    const int g = lane >> 4;
    const int b = (int)blockIdx.x;

    char* kbase = (char*)Klds;
    char* vbase = (char*)Vtlds;
    char* sbase = (char*)(Pscr + w * 1024);
    const float* xb = x + (size_t)b * TT * CC;

    short8 Qf[2][2];

    // ---------------- projection: per tile, sequential ----------------
#pragma unroll
    for (int tm = 0; tm < 2; ++tm) {
        const int gr = (tm == 0) ? 16 * w : 240 - 16 * w;
        f32x4 acc[3][4];
#pragma unroll
        for (int m = 0; m < 3; ++m)
#pragma unroll
            for (int nt = 0; nt < 4; ++nt)
                acc[m][nt] = (f32x4){0.f, 0.f, 0.f, 0.f};

        const float* prow = xb + (size_t)(gr + c) * CC + 8 * g;
#pragma unroll
        for (int kt = 0; kt < 12; ++kt) {
            f32x4 f0 = *(const f32x4*)(prow + 32 * kt);
            f32x4 f1 = *(const f32x4*)(prow + 32 * kt + 4);
            i32x4 aw = {(int)cvtpk(f0[0], f0[1]), (int)cvtpk(f0[2], f0[3]),
                        (int)cvtpk(f1[0], f1[1]), (int)cvtpk(f1[2], f1[3])};
            short8 afr = __builtin_bit_cast(short8, aw);
#pragma unroll
            for (int mat = 0; mat < 3; ++mat)
#pragma unroll
                for (int nt = 0; nt < 4; ++nt) {
                    short8 bfr = *(const short8*)(WbT + (size_t)(((mat * 12 + kt) * 4 + nt) * 64 + lane) * 8);
                    acc[mat][nt] = mfma16x16x32(afr, bfr, acc[mat][nt]);
                }
        }

        // Q: D-layout -> own K rows (scratch) -> B-fragments
#pragma unroll
        for (int nt = 0; nt < 4; ++nt)
#pragma unroll
            for (int r = 0; r < 4; ++r) {
                int q = gr + 4 * g + r;
                int hh = 16 * nt + c;
                *(u16*)(kbase + q * 128 + ((hh * 2) ^ ((q & 7) << 4))) = fbf(acc[0][nt][r]);
            }
#pragma unroll
        for (int kt = 0; kt < 2; ++kt) {
            int q = gr + c;
            Qf[tm][kt] = *(const short8*)(kbase + q * 128 + ((64 * kt + 16 * g) ^ ((q & 7) << 4)));
        }

        // K (overwrites Q scratch rows; same-wave DS ordering) and Vt
#pragma unroll
        for (int nt = 0; nt < 4; ++nt) {
            int hh = 16 * nt + c;
#pragma unroll
            for (int r = 0; r < 4; ++r) {
                int s = gr + 4 * g + r;
                *(u16*)(kbase + s * 128 + ((hh * 2) ^ ((s & 7) << 4))) = fbf(acc[1][nt][r]);
            }
            int sb4 = gr + 4 * g;
            u64 pkv = (u64)cvtpk(acc[2][nt][0], acc[2][nt][1]) |
                      ((u64)cvtpk(acc[2][nt][2], acc[2][nt][3]) << 32);
            *(u64*)(vbase + hh * 512 + ((sb4 * 2) ^ ((hh & 7) << 4))) = pkv;
        }
    }

    __syncthreads();

    // ---------------- attention: per tile, sequential ----------------
#pragma unroll
    for (int tm = 0; tm < 2; ++tm) {
        const int gr = (tm == 0) ? 16 * w : 240 - 16 * w;
        const int lastc = (gr + 15) >> 6;
        const int qg = gr + c;

        float m_run = -1e30f, l_run = 0.f;
        f32x4 o[4];
#pragma unroll
        for (int ht = 0; ht < 4; ++ht)
            o[ht] = (f32x4){0.f, 0.f, 0.f, 0.f};

        for (int ci = 0; ci <= lastc; ++ci) {
            const int s0 = 64 * ci;
            int stx = (gr + 15 - s0) >> 4;
            const int stmax = stx > 3 ? 3 : stx;
            const bool needMask = (s0 + 63 > gr);

            // S^T = K(16s x 32h) x Q^T(32h x 16q); lane: s-row = 4g+r, q-col = c
            f32x4 SS[4];
#pragma unroll
            for (int st = 0; st < 4; ++st)
                SS[st] = (f32x4){0.f, 0.f, 0.f, 0.f};
#pragma unroll
            for (int kt = 0; kt < 2; ++kt)
#pragma unroll
                for (int st = 0; st < 4; ++st)
                    if (st <= stmax) {
                        int s = s0 + 16 * st + c;
                        short8 kf = *(const short8*)(kbase + s * 128 + ((64 * kt + 16 * g) ^ ((s & 7) << 4)));
                        SS[st] = mfma16x16x32(kf, Qf[tm][kt], SS[st]);
                    }

            // mask (only chunks straddling the diagonal) + chunk max
            float mx = -1e30f;
#pragma unroll
            for (int st = 0; st < 4; ++st)
                if (st <= stmax)
#pragma unroll
                    for (int r = 0; r < 4; ++r) {
                        float v = SS[st][r];
                        if (needMask) {
                            int sg = s0 + 16 * st + 4 * g + r;
                            v = (sg > qg) ? -1e30f : v;
                            SS[st][r] = v;
                        }
                        mx = fmaxf(mx, v);
                    }
            mx = fmaxf(mx, __shfl_xor(mx, 16));
            mx = fmaxf(mx, __shfl_xor(mx, 32));

            float mn = fmaxf(m_run, mx);
            float fs = __expf(m_run - mn);
            m_run = mn;

            float ls = 0.f;
#pragma unroll
            for (int st = 0; st < 4; ++st)
                if (st <= stmax)
#pragma unroll
                    for (int r = 0; r < 4; ++r) {
                        float p = __expf(SS[st][r] - mn);
                        SS[st][r] = p;
                        ls += p;
                    }
            ls += __shfl_xor(ls, 16);
            ls += __shfl_xor(ls, 32);
            l_run = l_run * fs + ls;

            // rescale O (row j=4g+r gets fs from lane c'=j)
            if (ci) {
#pragma unroll
                for (int r = 0; r < 4; ++r) {
                    float fr = __shfl(fs, 4 * g + r);
#pragma unroll
                    for (int ht = 0; ht < 4; ++ht)
                        o[ht][r] *= fr;
                }
            }

            // P (bf16) -> per-wave scratch [16 q][64 s] (swizzled).
            // Must cover st <= (stmax|1): PV below reads whole 32-s blocks.
            const int stW = stmax | 1;
#pragma unroll
            for (int st = 0; st < 4; ++st)
                if (st <= stW) {
                    u64 pp = 0;
                    if (st <= stmax)
                        pp = (u64)cvtpk(SS[st][0], SS[st][1]) |
                             ((u64)cvtpk(SS[st][2], SS[st][3]) << 32);
                    *(u64*)(sbase + c * 128 + ((32 * st + 8 * g) ^ ((c & 7) << 4))) = pp;
                }

            // PV: O += P(16q x 32s) x V(32s x 16h)
            const int ksmax = stmax >> 1;
#pragma unroll
            for (int ks = 0; ks < 2; ++ks)
                if (ks <= ksmax) {
                    short8 Pf = *(const short8*)(sbase + c * 128 + ((64 * ks + 16 * g) ^ ((c & 7) << 4)));
#pragma unroll
                    for (int ht = 0; ht < 4; ++ht) {
                        int hh = 16 * ht + c;
                        short8 vf = *(const short8*)(vbase + hh * 512 + ((2 * s0 + 64 * ks + 16 * g) ^ ((hh & 7) << 4)));
                        o[ht] = mfma16x16x32(Pf, vf, o[ht]);
                    }
                }
        }

        // epilogue for this tile
        float ri = 1.f / l_run;
        float* ob = out + ((size_t)b * TT + gr) * HH;
#pragma unroll
        for (int r = 0; r < 4; ++r) {
            float rr = __shfl(ri, 4 * g + r);
#pragma unroll
            for (int ht = 0; ht < 4; ++ht)
                ob[(4 * g + r) * HH + 16 * ht + c] = o[ht][r] * rr;
        }
    }
}

extern "C" void kernel_launch(void* const* d_in, const int* in_sizes, int n_in,
                              void* d_out, int out_size, void* d_ws, size_t ws_size,
                              hipStream_t stream) {
    (void)in_sizes; (void)n_in; (void)out_size; (void)ws_size;
    const float* x = (const float*)d_in[0];
    const float* Wk = (const float*)d_in[1];
    const float* Wq = (const float*)d_in[2];
    const float* Wv = (const float*)d_in[3];
    u16* WbT = (u16*)d_ws;
    float* out = (float*)d_out;

    prep_w<<<36, 256, 0, stream>>>(Wk, Wq, Wv, WbT);
    attn_head<<<NB, 512, 0, stream>>>(x, WbT, out);
}

// Round 5
// 104.297 us; speedup vs baseline: 1.6796x; 1.2391x over previous
//
#include <hip/hip_runtime.h>

typedef __attribute__((ext_vector_type(4))) float f32x4;
typedef __attribute__((ext_vector_type(4))) int i32x4;
typedef __attribute__((ext_vector_type(8))) short short8;
typedef unsigned int u32;
typedef unsigned long long u64;
typedef unsigned short u16;

#define NB 512
#define TT 256
#define CC 384
#define HH 64

__device__ __forceinline__ u16 fbf(float f) {
    u32 u = __builtin_bit_cast(u32, f);
    u32 r = u + 0x7fffu + ((u >> 16) & 1u);
    return (u16)(r >> 16);
}

// pack two f32 -> two bf16 (RNE) in one instruction
__device__ __forceinline__ u32 cvtpk(float lo, float hi) {
    u32 r;
    asm("v_cvt_pk_bf16_f32 %0, %1, %2" : "=v"(r) : "v"(lo), "v"(hi));
    return r;
}

__device__ __forceinline__ f32x4 mfma16x16x32(short8 a, short8 b, f32x4 c) {
    return __builtin_amdgcn_mfma_f32_16x16x32_bf16(a, b, c, 0, 0, 0);
}

__device__ __forceinline__ short8 load_afr(const float* p) {
    f32x4 f0 = *(const f32x4*)p;
    f32x4 f1 = *(const f32x4*)(p + 4);
    i32x4 aw = {(int)cvtpk(f0[0], f0[1]), (int)cvtpk(f0[2], f0[3]),
                (int)cvtpk(f1[0], f1[1]), (int)cvtpk(f1[2], f1[3])};
    return __builtin_bit_cast(short8, aw);
}

// WbT layout: fragment fi = ((mat*12 + kt)*4 + nt); element (fi*64 + lane)*8 + j
//   = W[mat][c = 32*kt + 8*(lane>>4) + j][h = 16*nt + (lane&15)]
// mat 0 = Wq * 384^-0.5 (scale folded), 1 = Wk, 2 = Wv.
__global__ __launch_bounds__(256) void prep_w(const float* __restrict__ Wk,
                                              const float* __restrict__ Wq,
                                              const float* __restrict__ Wv,
                                              u16* __restrict__ WbT) {
    int t = blockIdx.x * 256 + threadIdx.x;
    if (t >= 144 * 64) return;
    int lane = t & 63;
    int fi = t >> 6;
    int mat = fi / 48;
    int kt = (fi >> 2) % 12;
    int nt = fi & 3;
    const float* W = (mat == 0) ? Wq : (mat == 1 ? Wk : Wv);
    float scale = (mat == 0) ? 0.05103103630798288f : 1.0f;
    int c0 = 32 * kt + 8 * (lane >> 4);
    int h = 16 * nt + (lane & 15);
#pragma unroll
    for (int j = 0; j < 8; ++j)
        WbT[(size_t)t * 8 + j] = fbf(W[(c0 + j) * HH + h] * scale);
}

// One block per batch, 8 waves, LDS 80KB -> 2 blocks/CU.
// Wave w owns two 16-row q-tiles: rows [16w,16w+16) and [240-16w,256-16w)
// (balanced causal work). Projection runs in two passes -- pass A computes
// Q,K for BOTH tiles per W-fragment load, pass B computes V for both --
// halving the per-wave WbT L2 traffic vs per-tile passes (288->144 KB).
// Attention is per-tile sequential (one tile's state live -> no spills).
// K row-major [256][64] bf16 (XOR-swizzled), Vt [64][256] bf16 (swizzled),
// per-wave 16x64 P scratch for the S^T D-layout -> PV A-frag reshape.
// NOTE: PV reads P s-blocks st <= (stmax|1); the P write loop MUST cover
// that range (zeros beyond stmax) -- reading unwritten LDS = round-3 NaN.
// NOTE: __launch_bounds__ min-arg on this toolchain acts like blocks/CU:
// (512,4) capped VGPRs at 64 and spilled (r2/r4); (512,2) -> cap 128.
__global__ __launch_bounds__(512, 2) void attn_head(const float* __restrict__ x,
                                                    const u16* __restrict__ WbT,
                                                    float* __restrict__ out) {
    __shared__ __align__(16) u16 Klds[TT * HH];      // 32 KB
    __shared__ __align__(16) u16 Vtlds[HH * TT];     // 32 KB
    __shared__ __align__(16) u16 Pscr[8 * 16 * 64];  // 16 KB

    const int tid = (int)threadIdx.x;
    const int lane = tid & 63;
    const int w = tid >> 6;
    const int c = lane & 15;
    const int g = lane >> 4;
    const int b = (int)blockIdx.x;
    const int gr0 = 16 * w;
    const int gr1 = 240 - 16 * w;

    char* kbase = (char*)Klds;
    char* vbase = (char*)Vtlds;
    char* sbase = (char*)(Pscr + w * 1024);
    const float* xb = x + (size_t)b * TT * CC;
    const float* prow0 = xb + (size_t)(gr0 + c) * CC + 8 * g;
    const float* prow1 = xb + (size_t)(gr1 + c) * CC + 8 * g;

    short8 Qf[2][2];

    // ---------------- pass A: Q and K for both tiles ----------------
    {
        f32x4 acc[2][2][4];  // [mat Q/K][tile][nt]
#pragma unroll
        for (int m = 0; m < 2; ++m)
#pragma unroll
            for (int t = 0; t < 2; ++t)
#pragma unroll
                for (int nt = 0; nt < 4; ++nt)
                    acc[m][t][nt] = (f32x4){0.f, 0.f, 0.f, 0.f};

        for (int kt = 0; kt < 12; ++kt) {
            short8 a0 = load_afr(prow0 + 32 * kt);
            short8 a1 = load_afr(prow1 + 32 * kt);
#pragma unroll
            for (int mat = 0; mat < 2; ++mat)
#pragma unroll
                for (int nt = 0; nt < 4; ++nt) {
                    short8 bfr = *(const short8*)(WbT + (size_t)(((mat * 12 + kt) * 4 + nt) * 64 + lane) * 8);
                    acc[mat][0][nt] = mfma16x16x32(a0, bfr, acc[mat][0][nt]);
                    acc[mat][1][nt] = mfma16x16x32(a1, bfr, acc[mat][1][nt]);
                }
        }

        // Q: D-layout -> own K rows (scratch) -> B-fragments, per tile
#pragma unroll
        for (int t = 0; t < 2; ++t) {
            const int gr = t ? gr1 : gr0;
#pragma unroll
            for (int nt = 0; nt < 4; ++nt)
#pragma unroll
                for (int r = 0; r < 4; ++r) {
                    int q = gr + 4 * g + r;
                    int hh = 16 * nt + c;
                    *(u16*)(kbase + q * 128 + ((hh * 2) ^ ((q & 7) << 4))) = fbf(acc[0][t][nt][r]);
                }
#pragma unroll
            for (int kt = 0; kt < 2; ++kt) {
                int q = gr + c;
                Qf[t][kt] = *(const short8*)(kbase + q * 128 + ((64 * kt + 16 * g) ^ ((q & 7) << 4)));
            }
        }

        // K rows (overwrite Q scratch; same-wave DS ordering is program order)
#pragma unroll
        for (int t = 0; t < 2; ++t) {
            const int gr = t ? gr1 : gr0;
#pragma unroll
            for (int nt = 0; nt < 4; ++nt) {
                int hh = 16 * nt + c;
#pragma unroll
                for (int r = 0; r < 4; ++r) {
                    int s = gr + 4 * g + r;
                    *(u16*)(kbase + s * 128 + ((hh * 2) ^ ((s & 7) << 4))) = fbf(acc[1][t][nt][r]);
                }
            }
        }
    }

    // ---------------- pass B: V for both tiles ----------------
    {
        f32x4 accV[2][4];
#pragma unroll
        for (int t = 0; t < 2; ++t)
#pragma unroll
            for (int nt = 0; nt < 4; ++nt)
                accV[t][nt] = (f32x4){0.f, 0.f, 0.f, 0.f};

        for (int kt = 0; kt < 12; ++kt) {
            short8 a0 = load_afr(prow0 + 32 * kt);
            short8 a1 = load_afr(prow1 + 32 * kt);
#pragma unroll
            for (int nt = 0; nt < 4; ++nt) {
                short8 bfr = *(const short8*)(WbT + (size_t)(((2 * 12 + kt) * 4 + nt) * 64 + lane) * 8);
                accV[0][nt] = mfma16x16x32(a0, bfr, accV[0][nt]);
                accV[1][nt] = mfma16x16x32(a1, bfr, accV[1][nt]);
            }
        }

#pragma unroll
        for (int t = 0; t < 2; ++t) {
            const int gr = t ? gr1 : gr0;
#pragma unroll
            for (int nt = 0; nt < 4; ++nt) {
                int hh = 16 * nt + c;
                int sb4 = gr + 4 * g;
                u64 pkv = (u64)cvtpk(accV[t][nt][0], accV[t][nt][1]) |
                          ((u64)cvtpk(accV[t][nt][2], accV[t][nt][3]) << 32);
                *(u64*)(vbase + hh * 512 + ((sb4 * 2) ^ ((hh & 7) << 4))) = pkv;
            }
        }
    }

    __syncthreads();

    // ---------------- attention: per tile, sequential ----------------
#pragma unroll
    for (int tm = 0; tm < 2; ++tm) {
        const int gr = (tm == 0) ? gr0 : gr1;
        const int lastc = (gr + 15) >> 6;
        const int qg = gr + c;

        float m_run = -1e30f, l_run = 0.f;
        f32x4 o[4];
#pragma unroll
        for (int ht = 0; ht < 4; ++ht)
            o[ht] = (f32x4){0.f, 0.f, 0.f, 0.f};

        for (int ci = 0; ci <= lastc; ++ci) {
            const int s0 = 64 * ci;
            int stx = (gr + 15 - s0) >> 4;
            const int stmax = stx > 3 ? 3 : stx;
            const bool needMask = (s0 + 63 > gr);

            // S^T = K(16s x 32h) x Q^T(32h x 16q); lane: s-row = 4g+r, q-col = c
            f32x4 SS[4];
#pragma unroll
            for (int st = 0; st < 4; ++st)
                SS[st] = (f32x4){0.f, 0.f, 0.f, 0.f};
#pragma unroll
            for (int kt = 0; kt < 2; ++kt)
#pragma unroll
                for (int st = 0; st < 4; ++st)
                    if (st <= stmax) {
                        int s = s0 + 16 * st + c;
                        short8 kf = *(const short8*)(kbase + s * 128 + ((64 * kt + 16 * g) ^ ((s & 7) << 4)));
                        SS[st] = mfma16x16x32(kf, Qf[tm][kt], SS[st]);
                    }

            // mask (only chunks straddling the diagonal) + chunk max
            float mx = -1e30f;
#pragma unroll
            for (int st = 0; st < 4; ++st)
                if (st <= stmax)
#pragma unroll
                    for (int r = 0; r < 4; ++r) {
                        float v = SS[st][r];
                        if (needMask) {
                            int sg = s0 + 16 * st + 4 * g + r;
                            v = (sg > qg) ? -1e30f : v;
                            SS[st][r] = v;
                        }
                        mx = fmaxf(mx, v);
                    }
            mx = fmaxf(mx, __shfl_xor(mx, 16));
            mx = fmaxf(mx, __shfl_xor(mx, 32));

            float mn = fmaxf(m_run, mx);
            float fs = __expf(m_run - mn);
            m_run = mn;

            float ls = 0.f;
#pragma unroll
            for (int st = 0; st < 4; ++st)
                if (st <= stmax)
#pragma unroll
                    for (int r = 0; r < 4; ++r) {
                        float p = __expf(SS[st][r] - mn);
                        SS[st][r] = p;
                        ls += p;
                    }
            ls += __shfl_xor(ls, 16);
            ls += __shfl_xor(ls, 32);
            l_run = l_run * fs + ls;

            // rescale O (row j=4g+r gets fs from lane c'=j)
            if (ci) {
#pragma unroll
                for (int r = 0; r < 4; ++r) {
                    float fr = __shfl(fs, 4 * g + r);
#pragma unroll
                    for (int ht = 0; ht < 4; ++ht)
                        o[ht][r] *= fr;
                }
            }

            // P (bf16) -> per-wave scratch [16 q][64 s] (swizzled).
            // Must cover st <= (stmax|1): PV below reads whole 32-s blocks.
            const int stW = stmax | 1;
#pragma unroll
            for (int st = 0; st < 4; ++st)
                if (st <= stW) {
                    u64 pp = 0;
                    if (st <= stmax)
                        pp = (u64)cvtpk(SS[st][0], SS[st][1]) |
                             ((u64)cvtpk(SS[st][2], SS[st][3]) << 32);
                    *(u64*)(sbase + c * 128 + ((32 * st + 8 * g) ^ ((c & 7) << 4))) = pp;
                }

            // PV: O += P(16q x 32s) x V(32s x 16h)
            const int ksmax = stmax >> 1;
#pragma unroll
            for (int ks = 0; ks < 2; ++ks)
                if (ks <= ksmax) {
                    short8 Pf = *(const short8*)(sbase + c * 128 + ((64 * ks + 16 * g) ^ ((c & 7) << 4)));
#pragma unroll
                    for (int ht = 0; ht < 4; ++ht) {
                        int hh = 16 * ht + c;
                        short8 vf = *(const short8*)(vbase + hh * 512 + ((2 * s0 + 64 * ks + 16 * g) ^ ((hh & 7) << 4)));
                        o[ht] = mfma16x16x32(Pf, vf, o[ht]);
                    }
                }
        }

        // epilogue for this tile
        float ri = 1.f / l_run;
        float* ob = out + ((size_t)b * TT + gr) * HH;
#pragma unroll
        for (int r = 0; r < 4; ++r) {
            float rr = __shfl(ri, 4 * g + r);
#pragma unroll
            for (int ht = 0; ht < 4; ++ht)
                ob[(4 * g + r) * HH + 16 * ht + c] = o[ht][r] * rr;
        }
    }
}

extern "C" void kernel_launch(void* const* d_in, const int* in_sizes, int n_in,
                              void* d_out, int out_size, void* d_ws, size_t ws_size,
                              hipStream_t stream) {
    (void)in_sizes; (void)n_in; (void)out_size; (void)ws_size;
    const float* x = (const float*)d_in[0];
    const float* Wk = (const float*)d_in[1];
    const float* Wq = (const float*)d_in[2];
    const float* Wv = (const float*)d_in[3];
    u16* WbT = (u16*)d_ws;
    float* out = (float*)d_out;

    prep_w<<<36, 256, 0, stream>>>(Wk, Wq, Wv, WbT);
    attn_head<<<NB, 512, 0, stream>>>(x, WbT, out);
}